// Round 8
// baseline (609.678 us; speedup 1.0000x reference)
//
#include <hip/hip_runtime.h>
#include <hip/hip_bf16.h>
#include <math.h>

#define S_LEN 8192
#define D_MODEL 768
#define D_RNN 1024
#define MLP_INNER 3072

typedef __attribute__((ext_vector_type(8))) short bf16x8;
typedef __attribute__((ext_vector_type(4))) float f32x4;
typedef unsigned short ushort_t;

#ifndef __has_builtin
#define __has_builtin(x) 0
#endif
#if __has_builtin(__builtin_amdgcn_global_load_lds)
#define HAS_ASYNC 1
#else
#define HAS_ASYNC 0
#endif

#define LOG2E 1.4426950408889634f

// fast sigmoid: 1/(1+2^(-x*log2e)); v_exp_f32 + v_rcp_f32, ~1ulp
__device__ __forceinline__ float fast_sigmoid(float x) {
    float e = __builtin_amdgcn_exp2f(-x * LOG2E);
    return __builtin_amdgcn_rcpf(1.0f + e);
}
// fast exp
__device__ __forceinline__ float fast_exp(float x) {
    return __builtin_amdgcn_exp2f(x * LOG2E);
}
// gelu(tanh approx) = v * sigmoid(2*0.7978845608*(v + 0.044715 v^3))
__device__ __forceinline__ float gelu_fast(float v) {
    float u = v * (1.5957691216057308f + 0.07135481283247183f * v * v);
    return v * fast_sigmoid(u);
}
__device__ __forceinline__ float us2f(ushort_t u) { return __uint_as_float(((unsigned)u) << 16); }
__device__ __forceinline__ ushort_t f2us(float f) {
    __hip_bfloat16 b = __float2bfloat16(f);
    return *(ushort_t*)&b;
}

// async 16B global -> LDS (wave-uniform LDS base; HW adds lane*16B)
__device__ __forceinline__ void cp16(const ushort_t* g, ushort_t* l) {
#if HAS_ASYNC
    __builtin_amdgcn_global_load_lds((__attribute__((address_space(1))) void*)g,
                                     (__attribute__((address_space(3))) void*)l,
                                     16, 0, 0);
#endif
}

// ---------------------------------------------------------------------------
// One-shot weight conversion fp32 -> bf16 (all weights) + nl
// ---------------------------------------------------------------------------
__global__ __launch_bounds__(256) void cvt_all(const float* __restrict__ w_lin1,
                                               const float* __restrict__ w_conv,
                                               const float* __restrict__ w_rg,
                                               const float* __restrict__ w_out,
                                               const float* __restrict__ w_m1,
                                               const float* __restrict__ w_m2,
                                               const float* __restrict__ Lambda,
                                               ushort_t* __restrict__ wb,
                                               float* __restrict__ nl) {
    int idx = blockIdx.x * 256 + threadIdx.x;
    if (idx < 1572864) {
        wb[idx] = f2us(w_lin1[idx]);
    } else if (idx < 5767168) {
        int d = idx - 1572864;
        int i2 = d & 1023, dk = (d >> 10) & 3, o = d >> 12;
        wb[idx] = f2us(w_conv[(size_t)o * 4096 + i2 * 4 + dk]);
    } else if (idx < 7864320) {
        wb[idx] = f2us(w_rg[idx - 5767168]);
    } else if (idx < 8650752) {
        wb[idx] = f2us(w_out[idx - 7864320]);
    } else if (idx < 13369344) {
        wb[idx] = f2us(w_m1[idx - 8650752]);
    } else if (idx < 15728640) {
        wb[idx] = f2us(w_m2[idx - 13369344]);
    } else {
        int c = idx - 15728640;
        if (c < D_RNN) nl[c] = -8.0f * log1pf(expf(Lambda[c]));
    }
}

// ---------------------------------------------------------------------------
// RMSNorm fp32 in -> bf16 out. One wave per row (768 = 64 lanes x 3 float4),
// 4 rows per block. Row lives in registers: float4 loads, shfl butterfly
// reduce, no LDS / no syncthreads, packed 8B bf16 stores. (G13 + G1)
// ---------------------------------------------------------------------------
__global__ __launch_bounds__(256) void rms_kernel(const float* __restrict__ x,
                                                  const float* __restrict__ w,
                                                  ushort_t* __restrict__ o, int D) {
    int wid = threadIdx.x >> 6, lane = threadIdx.x & 63;
    int row = blockIdx.x * 4 + wid;
    const float4* xr = (const float4*)(x + (size_t)row * 768);
    const float4* wr = (const float4*)w;
    float4 v0 = xr[lane], v1 = xr[lane + 64], v2 = xr[lane + 128];
    float ss = v0.x * v0.x + v0.y * v0.y + v0.z * v0.z + v0.w * v0.w +
               v1.x * v1.x + v1.y * v1.y + v1.z * v1.z + v1.w * v1.w +
               v2.x * v2.x + v2.y * v2.y + v2.z * v2.z + v2.w * v2.w;
#pragma unroll
    for (int off = 32; off > 0; off >>= 1) ss += __shfl_xor(ss, off);
    float s = rsqrtf(ss * (1.0f / 768.0f) + 1e-5f);
    float4 w0 = wr[lane], w1 = wr[lane + 64], w2 = wr[lane + 128];
    ushort_t* orow = o + (size_t)row * 768;
    ushort4 u0 = {f2us(v0.x * s * w0.x), f2us(v0.y * s * w0.y),
                  f2us(v0.z * s * w0.z), f2us(v0.w * s * w0.w)};
    ushort4 u1 = {f2us(v1.x * s * w1.x), f2us(v1.y * s * w1.y),
                  f2us(v1.z * s * w1.z), f2us(v1.w * s * w1.w)};
    ushort4 u2 = {f2us(v2.x * s * w2.x), f2us(v2.y * s * w2.y),
                  f2us(v2.z * s * w2.z), f2us(v2.w * s * w2.w)};
    *(ushort4*)&orow[4 * lane] = u0;
    *(ushort4*)&orow[256 + 4 * lane] = u1;
    *(ushort4*)&orow[512 + 4 * lane] = u2;
}

// ---------------------------------------------------------------------------
// MFMA bf16 NT GEMM, 128xBN_ tile, 4 waves (2x2), BK=64.
// NBUF=2 (non-dual): 2-phase double buffer, STAGE(next) before compute(cur),
//   one barrier per K-step (verified win on long-K / non-dual steps, r7).
// NBUF=1 (dual): single buffer (dbuf measured NULL on dual, r7); BN_=128
//   raises arithmetic intensity: 256 MFMA / 48KB staged per iter (+33%),
//   ds_read/MFMA 0.5 -> 0.375.
// Staging swizzle: thread owns (srow=tid>>3, slot=tid&7); LDS row r slot s
// holds global 16B-chunk s^(r&7). Fragment read: chunk (h*4+quad)^(l16&7).
// AMODE 0: A[M,K] bf16 row-major.  AMODE 1: conv im2col, element (m,k) =
//   abb[(m-3)*1024 + k]; m0==0 staged manually with zero-guard.
// EMODE 0: bf16 -> Cb[M,N]
// EMODE 1: +bias, split halves -> Cb (n<1024), Cb2 (n>=1024), stride 1024
// EMODE 2: +bias +resid -> fp32 Cf[M,N]
// EMODE 3: dual-B gates -> bf16 a=Cb, gx=Cb2 (stride 1024)
// EMODE 4: dual-B geglu: Cb[m*3072+n] = gelu(acc1+b1)*(acc2+b2)
// ---------------------------------------------------------------------------
template <int BN_, int AMODE, int EMODE>
__global__ __launch_bounds__(256) void mfma_nt(const ushort_t* __restrict__ A,
                                               const ushort_t* __restrict__ B,
                                               const ushort_t* __restrict__ B2,
                                               const float* __restrict__ bias,
                                               const float* __restrict__ bias2,
                                               const float* __restrict__ resid,
                                               const float* __restrict__ nl,
                                               const ushort_t* __restrict__ cv,
                                               float* __restrict__ Cf,
                                               ushort_t* __restrict__ Cb,
                                               ushort_t* __restrict__ Cb2,
                                               int M, int N, int K) {
    constexpr bool DUAL = (EMODE == 3 || EMODE == 4);
    constexpr int NBUF = DUAL ? 1 : 2;     // dual: single-buf (dbuf null, r7)
    constexpr int NT = BN_ / 32;           // n-tiles per wave
    constexpr int BPASS = BN_ / 32;        // 32-row staging passes for B
    __shared__ ushort_t As[NBUF][128 * 64];
    __shared__ ushort_t Bs[NBUF][BN_ * 64];
    __shared__ ushort_t B2s[DUAL ? NBUF : 1][DUAL ? BN_ * 64 : 8];

    int tid = threadIdx.x;
    int wave = tid >> 6, lane = tid & 63;
    int quad = lane >> 4, l16 = lane & 15;
    int wm = (wave >> 1) * 64, wn = (wave & 1) * (BN_ / 2);
    int m0 = blockIdx.x * 128, n0 = blockIdx.y * BN_;
    int srow = tid >> 3;                      // staging row 0..31 (per pass)
    int scol = (((tid & 7) ^ (srow & 7)) * 8); // XOR-swizzled staging k-offset

    const int strideA = (AMODE == 0) ? K : 1024;
    const ushort_t* gA = A + (size_t)(m0 + srow - (AMODE == 1 ? 3 : 0)) * strideA + scol;
    const ushort_t* gB = B + (size_t)(n0 + srow) * K + scol;
    const ushort_t* gB2 = DUAL ? (B2 + (size_t)(n0 + srow) * K + scol) : nullptr;

    f32x4 acc[4][NT] = {};
    f32x4 acc2[DUAL ? 4 : 1][DUAL ? NT : 1] = {};

    // ---- staging helper: fill buffer b with K-tile at k0 ----
    auto stage = [&](int b, int k0) {
#if HAS_ASYNC
#pragma unroll
        for (int p = 0; p < BPASS; p++)
            cp16(gB + (size_t)p * 32 * K + k0, &Bs[b][(p * 32 + wave * 8) * 64]);
        if constexpr (DUAL) {
#pragma unroll
            for (int p = 0; p < BPASS; p++)
                cp16(gB2 + (size_t)p * 32 * K + k0, &B2s[b][(p * 32 + wave * 8) * 64]);
        }
#else
#pragma unroll
        for (int p = 0; p < BPASS; p++)
            *(uint4*)&Bs[b][(p * 32 + srow) * 64 + (tid & 7) * 8] =
                *(const uint4*)(gB + (size_t)p * 32 * K + k0);
        if constexpr (DUAL) {
#pragma unroll
            for (int p = 0; p < BPASS; p++)
                *(uint4*)&B2s[b][(p * 32 + srow) * 64 + (tid & 7) * 8] =
                    *(const uint4*)(gB2 + (size_t)p * 32 * K + k0);
        }
#endif
        if ((AMODE == 1) && (m0 == 0)) {
            // manual staging with zero-guard (rows m-3+dk < 0)
            int kg = k0 + scol;
            int dk = kg >> 10, ii = kg & 1023;
#pragma unroll
            for (int p = 0; p < 4; p++) {
                int msrc = p * 32 + srow + dk - 3;
                uint4 v = {0, 0, 0, 0};
                if (msrc >= 0)
                    v = *(const uint4*)(A + (size_t)msrc * 1024 + ii);
                *(uint4*)&As[b][(p * 32 + srow) * 64 + (tid & 7) * 8] = v;
            }
        } else {
#if HAS_ASYNC
#pragma unroll
            for (int p = 0; p < 4; p++)
                cp16(gA + (size_t)p * 32 * strideA + k0, &As[b][(p * 32 + wave * 8) * 64]);
#else
#pragma unroll
            for (int p = 0; p < 4; p++)
                *(uint4*)&As[b][(p * 32 + srow) * 64 + (tid & 7) * 8] =
                    *(const uint4*)(gA + (size_t)p * 32 * strideA + k0);
#endif
        }
    };

    // ---- compute helper: MFMA over buffer b ----
    auto compute = [&](int b) {
#pragma unroll
        for (int h = 0; h < 2; h++) {
            bf16x8 af[4], bfv[NT], bf2v[NT];
            int so = (((h * 4 + quad) ^ (l16 & 7)) << 3); // swizzled elem offset
#pragma unroll
            for (int i = 0; i < 4; i++)
                af[i] = *(const bf16x8*)&As[b][(wm + i * 16 + l16) * 64 + so];
#pragma unroll
            for (int j = 0; j < NT; j++) {
                bfv[j] = *(const bf16x8*)&Bs[b][(wn + j * 16 + l16) * 64 + so];
                if constexpr (DUAL)
                    bf2v[j] = *(const bf16x8*)&B2s[b][(wn + j * 16 + l16) * 64 + so];
            }
#pragma unroll
            for (int i = 0; i < 4; i++)
#pragma unroll
                for (int j = 0; j < NT; j++) {
                    acc[i][j] = __builtin_amdgcn_mfma_f32_16x16x32_bf16(af[i], bfv[j],
                                                                       acc[i][j], 0, 0, 0);
                    if constexpr (DUAL)
                        acc2[i][j] = __builtin_amdgcn_mfma_f32_16x16x32_bf16(af[i], bf2v[j],
                                                                            acc2[i][j], 0, 0, 0);
                }
        }
    };

    if constexpr (NBUF == 1) {
        for (int k0 = 0; k0 < K; k0 += 64) {
            stage(0, k0);
            __syncthreads();
            compute(0);
            __syncthreads();
        }
    } else {
        stage(0, 0);
        __syncthreads();   // buf0 ready
        int cur = 0;
        for (int k0 = 0; k0 < K; k0 += 64) {
            if (k0 + 64 < K) stage(cur ^ 1, k0 + 64);   // issue next tile EARLY
            compute(cur);
            __syncthreads();   // drains stage loads; retires buf reads
            cur ^= 1;
        }
    }

    // ---- epilogue: C/D layout col=lane&15, row=quad*4+reg ----
#pragma unroll
    for (int i = 0; i < 4; i++) {
        int mb = m0 + wm + i * 16 + quad * 4;
#pragma unroll
        for (int j = 0; j < NT; j++) {
            int n = n0 + wn + j * 16 + l16;
#pragma unroll
            for (int rg = 0; rg < 4; rg++) {
                int m = mb + rg;
                float v = acc[i][j][rg];
                if constexpr (EMODE == 0) {
                    Cb[(size_t)m * N + n] = f2us(v);
                } else if constexpr (EMODE == 1) {
                    v += bias[n];
                    if (n < 1024) Cb[((size_t)m << 10) + n] = f2us(v);
                    else          Cb2[((size_t)m << 10) + (n - 1024)] = f2us(v);
                } else if constexpr (EMODE == 2) {
                    v += bias[n];
                    if (resid) v += resid[(size_t)m * N + n];
                    Cf[(size_t)m * N + n] = v;
                } else if constexpr (EMODE == 3) {
                    float ig = fast_sigmoid(v + bias[n]);
                    float rgv = fast_sigmoid(acc2[i][j][rg] + bias2[n]);
                    float av = fast_exp(nl[n] * rgv);
                    size_t id = ((size_t)m << 10) + n;
                    Cb[id] = f2us(av);
                    Cb2[id] = f2us(sqrtf(fmaxf(1.0f - av * av, 0.0f)) * ig * us2f(cv[id]));
                } else { // EMODE 4
                    float v1 = gelu_fast(v + bias[n]);
                    float v2 = acc2[i][j][rg] + bias2[n];
                    Cb[(size_t)m * 3072 + n] = f2us(v1 * v2);
                }
            }
        }
    }
}

// ---------------------------------------------------------------------------
// Chunked linear scan over bf16 a/gx: h_t = a_t*h_{t-1} + gx_t.
// 256 chunks x 32 steps (G1: 512 blocks = 2/CU). 2 channels/thread via 4B
// uint loads (G13). Pass 3 fuses z = gelu(aba)*h (packed 4B stores).
// ---------------------------------------------------------------------------
#define NCHUNK 256
#define CHLEN 32

__global__ __launch_bounds__(256) void scan_pass1(const ushort_t* __restrict__ a16,
                                                  const ushort_t* __restrict__ g16,
                                                  float* __restrict__ Ac,
                                                  float* __restrict__ Bc) {
    int g = blockIdx.x * 256 + threadIdx.x;  // 131072 threads
    int cp = g & 511, ck = g >> 9;           // channel-pair, chunk
    int ch = cp * 2;
    size_t base = (((size_t)ck * CHLEN) << 10) + ch;
    const uint* ap = (const uint*)(a16 + base);
    const uint* gp = (const uint*)(g16 + base);
    float P0 = 1.0f, P1 = 1.0f, B0 = 0.0f, B1 = 0.0f;
#pragma unroll 8
    for (int t = 0; t < CHLEN; t++) {
        uint ua = ap[t * 512];
        uint ug = gp[t * 512];
        float a0 = us2f((ushort_t)ua), a1 = us2f((ushort_t)(ua >> 16));
        float g0 = us2f((ushort_t)ug), g1 = us2f((ushort_t)(ug >> 16));
        P0 *= a0; B0 = fmaf(a0, B0, g0);
        P1 *= a1; B1 = fmaf(a1, B1, g1);
    }
    float2 pv = {P0, P1}, bv = {B0, B1};
    *(float2*)&Ac[ck * 1024 + ch] = pv;
    *(float2*)&Bc[ck * 1024 + ch] = bv;
}

__global__ __launch_bounds__(256) void scan_pass2(const float* __restrict__ Ac,
                                                  const float* __restrict__ Bc,
                                                  float* __restrict__ Hc) {
    int ch = blockIdx.x * 256 + threadIdx.x; // 1024
    float H = 0.0f;
#pragma unroll 8
    for (int j = 0; j < NCHUNK; j++) {
        Hc[j * 1024 + ch] = H;
        H = fmaf(Ac[j * 1024 + ch], H, Bc[j * 1024 + ch]);
    }
}

__global__ __launch_bounds__(256) void scan_pass3(const ushort_t* __restrict__ a16,
                                                  const ushort_t* __restrict__ g16,
                                                  const float* __restrict__ Hc,
                                                  const ushort_t* __restrict__ aba,
                                                  ushort_t* __restrict__ z) {
    int g = blockIdx.x * 256 + threadIdx.x;
    int cp = g & 511, ck = g >> 9;
    int ch = cp * 2;
    size_t base = (((size_t)ck * CHLEN) << 10) + ch;
    float s0 = Hc[ck * 1024 + ch], s1 = Hc[ck * 1024 + ch + 1];
    const uint* ap = (const uint*)(a16 + base);
    const uint* gp = (const uint*)(g16 + base);
    const uint* bp = (const uint*)(aba + base);
    uint* zp = (uint*)(z + base);
#pragma unroll 8
    for (int t = 0; t < CHLEN; t++) {
        uint ua = ap[t * 512], ug = gp[t * 512], ub = bp[t * 512];
        s0 = fmaf(us2f((ushort_t)ua), s0, us2f((ushort_t)ug));
        s1 = fmaf(us2f((ushort_t)(ua >> 16)), s1, us2f((ushort_t)(ug >> 16)));
        float z0 = gelu_fast(us2f((ushort_t)ub)) * s0;
        float z1 = gelu_fast(us2f((ushort_t)(ub >> 16))) * s1;
        zp[t * 512] = (uint)f2us(z0) | ((uint)f2us(z1) << 16);
    }
}

// ---------------------------------------------------------------------------
extern "C" void kernel_launch(void* const* d_in, const int* in_sizes, int n_in,
                              void* d_out, int out_size, void* d_ws, size_t ws_size,
                              hipStream_t stream) {
    const float* x      = (const float*)d_in[0];
    const float* w_n1   = (const float*)d_in[1];
    const float* w_n2   = (const float*)d_in[2];
    const float* w_lin1 = (const float*)d_in[3];
    const float* b_lin1 = (const float*)d_in[4];
    const float* w_conv = (const float*)d_in[5];
    const float* w_rg   = (const float*)d_in[6];
    const float* b_rg   = (const float*)d_in[7];
    const float* Lambda = (const float*)d_in[8];
    const float* w_out  = (const float*)d_in[9];
    const float* b_out  = (const float*)d_in[10];
    const float* w_m1   = (const float*)d_in[11];
    const float* b_m1   = (const float*)d_in[12];
    const float* w_m2   = (const float*)d_in[13];
    const float* b_m2   = (const float*)d_in[14];

    char* ws = (char*)d_ws;
    const size_t MB = 1024ull * 1024ull;
    // Peak footprint 184 MB (<208 proven safe).
    ushort_t* wb   = (ushort_t*)(ws + 0);
    float*    x1   = (float*)(ws + 32 * MB);
    float*    nl   = (float*)(ws + 56 * MB);
    ushort_t* h16  = (ushort_t*)(ws + 57 * MB);
    ushort_t* aba  = (ushort_t*)(ws + 69 * MB);
    ushort_t* abb  = (ushort_t*)(ws + 85 * MB);
    ushort_t* z16  = (ushort_t*)(ws + 85 * MB);
    ushort_t* cv16 = (ushort_t*)(ws + 101 * MB);
    ushort_t* a16  = (ushort_t*)(ws + 117 * MB);
    ushort_t* gx16 = (ushort_t*)(ws + 133 * MB);
    ushort_t* gm   = (ushort_t*)(ws + 117 * MB);
    float*    Ac   = (float*)(ws + 181 * MB);
    float*    Bc   = (float*)(ws + 182 * MB);
    float*    Hc   = (float*)(ws + 183 * MB);
    float*    out  = (float*)d_out;

    ushort_t* wb_lin1 = wb + 0;          // 2048*768
    ushort_t* wb_conv = wb + 1572864;    // 1024*4096 (reordered)
    ushort_t* wb_rg   = wb + 5767168;    // 2048*1024
    ushort_t* wb_out  = wb + 7864320;    // 768*1024
    ushort_t* wb_m1   = wb + 8650752;    // 6144*768
    ushort_t* wb_m2   = wb + 13369344;   // 768*3072

    const int M = S_LEN;

    // 0. all weight conversions + nl in one launch
    cvt_all<<<61444, 256, 0, stream>>>(w_lin1, w_conv, w_rg, w_out, w_m1, w_m2,
                                       Lambda, wb, nl);
    // 1. h = rms(x, w_n1)  (4 rows/block, wave-per-row)
    rms_kernel<<<M / 4, 256, 0, stream>>>(x, w_n1, h16, D_MODEL);
    // 2. ab = h @ w_lin1^T + b_lin1, split -> aba/abb  (N=2048, K=768)
    mfma_nt<128, 0, 1><<<dim3(M / 128, 2048 / 128), 256, 0, stream>>>(
        h16, wb_lin1, nullptr, b_lin1, nullptr, nullptr, nullptr, nullptr,
        nullptr, aba, abb, M, 2048, 768);
    // 3. conv = im2col(abb) @ wb_conv^T -> cv16  (N=1024, K=4096, fused gather)
    mfma_nt<128, 1, 0><<<dim3(M / 128, 1024 / 128), 256, 0, stream>>>(
        abb, wb_conv, nullptr, nullptr, nullptr, nullptr, nullptr, nullptr,
        nullptr, cv16, nullptr, M, 1024, 4096);
    // 4. dual-B gates GEMM + gate math -> a16, gx16 bf16  (N'=1024, K=1024, BN=128)
    mfma_nt<128, 0, 3><<<dim3(M / 128, 1024 / 128), 256, 0, stream>>>(
        cv16, wb_rg, wb_rg + 1024 * 1024, b_rg, b_rg + 1024, nullptr, nl, cv16,
        nullptr, a16, gx16, M, 1024, 1024);
    // 5. chunked scan; pass3 fuses z = gelu(aba)*h -> z16
    scan_pass1<<<512, 256, 0, stream>>>(a16, gx16, Ac, Bc);
    scan_pass2<<<4, 256, 0, stream>>>(Ac, Bc, Hc);
    scan_pass3<<<512, 256, 0, stream>>>(a16, gx16, Hc, aba, z16);
    // 6. x1 = z @ w_out^T + b_out + x  (N=768, K=1024, fp32)
    mfma_nt<64, 0, 2><<<dim3(M / 128, 768 / 64), 256, 0, stream>>>(
        z16, wb_out, nullptr, b_out, nullptr, x, nullptr, nullptr,
        x1, nullptr, nullptr, M, 768, 1024);
    // 7. h2 = rms(x1, w_n2)
    rms_kernel<<<M / 4, 256, 0, stream>>>(x1, w_n2, h16, D_MODEL);
    // 8. dual-B MLP up-proj + GeGLU -> gm bf16  (N'=3072, K=768, BN=128)
    mfma_nt<128, 0, 4><<<dim3(M / 128, 3072 / 128), 256, 0, stream>>>(
        h16, wb_m1, wb_m1 + 3072 * 768, b_m1, b_m1 + 3072, nullptr, nullptr, nullptr,
        nullptr, gm, nullptr, M, 3072, 768);
    // 9. out = gm @ w_m2^T + b_m2 + x1  (N=768, K=3072, fp32)
    mfma_nt<64, 0, 2><<<dim3(M / 128, 768 / 64), 256, 0, stream>>>(
        gm, wb_m2, nullptr, b_m2, nullptr, x1, nullptr, nullptr,
        out, nullptr, nullptr, M, 768, 3072);
}

// Round 9
// 544.470 us; speedup vs baseline: 1.1198x; 1.1198x over previous
//
#include <hip/hip_runtime.h>
#include <hip/hip_bf16.h>
#include <math.h>

#define S_LEN 8192
#define D_MODEL 768
#define D_RNN 1024
#define MLP_INNER 3072

typedef __attribute__((ext_vector_type(8))) short bf16x8;
typedef __attribute__((ext_vector_type(4))) float f32x4;
typedef unsigned short ushort_t;

#ifndef __has_builtin
#define __has_builtin(x) 0
#endif
#if __has_builtin(__builtin_amdgcn_global_load_lds)
#define HAS_ASYNC 1
#else
#define HAS_ASYNC 0
#endif

#define LOG2E 1.4426950408889634f

// fast sigmoid: 1/(1+2^(-x*log2e)); v_exp_f32 + v_rcp_f32, ~1ulp
__device__ __forceinline__ float fast_sigmoid(float x) {
    float e = __builtin_amdgcn_exp2f(-x * LOG2E);
    return __builtin_amdgcn_rcpf(1.0f + e);
}
// fast exp
__device__ __forceinline__ float fast_exp(float x) {
    return __builtin_amdgcn_exp2f(x * LOG2E);
}
// gelu(tanh approx) = v * sigmoid(2*0.7978845608*(v + 0.044715 v^3))
__device__ __forceinline__ float gelu_fast(float v) {
    float u = v * (1.5957691216057308f + 0.07135481283247183f * v * v);
    return v * fast_sigmoid(u);
}
__device__ __forceinline__ float us2f(ushort_t u) { return __uint_as_float(((unsigned)u) << 16); }
__device__ __forceinline__ ushort_t f2us(float f) {
    __hip_bfloat16 b = __float2bfloat16(f);
    return *(ushort_t*)&b;
}

// async 16B global -> LDS (wave-uniform LDS base; HW adds lane*16B)
__device__ __forceinline__ void cp16(const ushort_t* g, ushort_t* l) {
#if HAS_ASYNC
    __builtin_amdgcn_global_load_lds((__attribute__((address_space(1))) void*)g,
                                     (__attribute__((address_space(3))) void*)l,
                                     16, 0, 0);
#endif
}

// ---------------------------------------------------------------------------
// One-shot weight conversion fp32 -> bf16 (all weights) + nl
// ---------------------------------------------------------------------------
__global__ __launch_bounds__(256) void cvt_all(const float* __restrict__ w_lin1,
                                               const float* __restrict__ w_conv,
                                               const float* __restrict__ w_rg,
                                               const float* __restrict__ w_out,
                                               const float* __restrict__ w_m1,
                                               const float* __restrict__ w_m2,
                                               const float* __restrict__ Lambda,
                                               ushort_t* __restrict__ wb,
                                               float* __restrict__ nl) {
    int idx = blockIdx.x * 256 + threadIdx.x;
    if (idx < 1572864) {
        wb[idx] = f2us(w_lin1[idx]);
    } else if (idx < 5767168) {
        int d = idx - 1572864;
        int i2 = d & 1023, dk = (d >> 10) & 3, o = d >> 12;
        wb[idx] = f2us(w_conv[(size_t)o * 4096 + i2 * 4 + dk]);
    } else if (idx < 7864320) {
        wb[idx] = f2us(w_rg[idx - 5767168]);
    } else if (idx < 8650752) {
        wb[idx] = f2us(w_out[idx - 7864320]);
    } else if (idx < 13369344) {
        wb[idx] = f2us(w_m1[idx - 8650752]);
    } else if (idx < 15728640) {
        wb[idx] = f2us(w_m2[idx - 13369344]);
    } else {
        int c = idx - 15728640;
        if (c < D_RNN) nl[c] = -8.0f * log1pf(expf(Lambda[c]));
    }
}

// ---------------------------------------------------------------------------
// RMSNorm fp32 in -> bf16 out. One wave per row (768 = 64 lanes x 3 float4),
// 4 rows per block. Row lives in registers: float4 loads, shfl butterfly
// reduce, no LDS / no syncthreads, packed 8B bf16 stores. (G13 + G1)
// ---------------------------------------------------------------------------
__global__ __launch_bounds__(256) void rms_kernel(const float* __restrict__ x,
                                                  const float* __restrict__ w,
                                                  ushort_t* __restrict__ o, int D) {
    int wid = threadIdx.x >> 6, lane = threadIdx.x & 63;
    int row = blockIdx.x * 4 + wid;
    const float4* xr = (const float4*)(x + (size_t)row * 768);
    const float4* wr = (const float4*)w;
    float4 v0 = xr[lane], v1 = xr[lane + 64], v2 = xr[lane + 128];
    float ss = v0.x * v0.x + v0.y * v0.y + v0.z * v0.z + v0.w * v0.w +
               v1.x * v1.x + v1.y * v1.y + v1.z * v1.z + v1.w * v1.w +
               v2.x * v2.x + v2.y * v2.y + v2.z * v2.z + v2.w * v2.w;
#pragma unroll
    for (int off = 32; off > 0; off >>= 1) ss += __shfl_xor(ss, off);
    float s = rsqrtf(ss * (1.0f / 768.0f) + 1e-5f);
    float4 w0 = wr[lane], w1 = wr[lane + 64], w2 = wr[lane + 128];
    ushort_t* orow = o + (size_t)row * 768;
    ushort4 u0 = {f2us(v0.x * s * w0.x), f2us(v0.y * s * w0.y),
                  f2us(v0.z * s * w0.z), f2us(v0.w * s * w0.w)};
    ushort4 u1 = {f2us(v1.x * s * w1.x), f2us(v1.y * s * w1.y),
                  f2us(v1.z * s * w1.z), f2us(v1.w * s * w1.w)};
    ushort4 u2 = {f2us(v2.x * s * w2.x), f2us(v2.y * s * w2.y),
                  f2us(v2.z * s * w2.z), f2us(v2.w * s * w2.w)};
    *(ushort4*)&orow[4 * lane] = u0;
    *(ushort4*)&orow[256 + 4 * lane] = u1;
    *(ushort4*)&orow[512 + 4 * lane] = u2;
}

// ---------------------------------------------------------------------------
// MFMA bf16 NT GEMM, 128xBN_ tile, 4 waves (2x2), BK=64.
// NBUF=2 (non-dual): 2-phase double buffer, STAGE(next) before compute(cur),
//   one barrier per K-step (verified win on long-K / non-dual steps, r7).
// NBUF=1 (dual): single buffer, BN=64 ONLY (r8: BN=128-dual -> 280 regs/lane
//   via unified VGPR+AGPR -> 1 wave/SIMD -> -67% regression. Dual caps at
//   NT=2.)  Dbuf also measured null on dual (r7: 102.4 vs 101.6).
// Staging swizzle: thread owns (srow=tid>>3, slot=tid&7); LDS row r slot s
// holds global 16B-chunk s^(r&7). Fragment read: chunk (h*4+quad)^(l16&7).
// AMODE 0: A[M,K] bf16 row-major.  AMODE 1: conv im2col, element (m,k) =
//   abb[(m-3)*1024 + k]; m0==0 staged manually with zero-guard.
// EMODE 0: bf16 -> Cb[M,N]
// EMODE 1: +bias, split halves -> Cb (n<1024), Cb2 (n>=1024), stride 1024
// EMODE 2: +bias +resid -> fp32 Cf[M,N]
// EMODE 3: dual-B gates -> bf16 a=Cb, gx=Cb2 (stride 1024)
// EMODE 4: dual-B geglu: Cb[m*3072+n] = gelu(acc1+b1)*(acc2+b2)
// ---------------------------------------------------------------------------
template <int BN_, int AMODE, int EMODE>
__global__ __launch_bounds__(256) void mfma_nt(const ushort_t* __restrict__ A,
                                               const ushort_t* __restrict__ B,
                                               const ushort_t* __restrict__ B2,
                                               const float* __restrict__ bias,
                                               const float* __restrict__ bias2,
                                               const float* __restrict__ resid,
                                               const float* __restrict__ nl,
                                               const ushort_t* __restrict__ cv,
                                               float* __restrict__ Cf,
                                               ushort_t* __restrict__ Cb,
                                               ushort_t* __restrict__ Cb2,
                                               int M, int N, int K) {
    constexpr bool DUAL = (EMODE == 3 || EMODE == 4);
    constexpr int NBUF = DUAL ? 1 : 2;     // dual: single-buf (dbuf null, r7)
    constexpr int NT = BN_ / 32;           // n-tiles per wave
    constexpr int BPASS = BN_ / 32;        // 32-row staging passes for B
    __shared__ ushort_t As[NBUF][128 * 64];
    __shared__ ushort_t Bs[NBUF][BN_ * 64];
    __shared__ ushort_t B2s[DUAL ? NBUF : 1][DUAL ? BN_ * 64 : 8];

    int tid = threadIdx.x;
    int wave = tid >> 6, lane = tid & 63;
    int quad = lane >> 4, l16 = lane & 15;
    int wm = (wave >> 1) * 64, wn = (wave & 1) * (BN_ / 2);
    int m0 = blockIdx.x * 128, n0 = blockIdx.y * BN_;
    int srow = tid >> 3;                      // staging row 0..31 (per pass)
    int scol = (((tid & 7) ^ (srow & 7)) * 8); // XOR-swizzled staging k-offset

    const int strideA = (AMODE == 0) ? K : 1024;
    const ushort_t* gA = A + (size_t)(m0 + srow - (AMODE == 1 ? 3 : 0)) * strideA + scol;
    const ushort_t* gB = B + (size_t)(n0 + srow) * K + scol;
    const ushort_t* gB2 = DUAL ? (B2 + (size_t)(n0 + srow) * K + scol) : nullptr;

    f32x4 acc[4][NT] = {};
    f32x4 acc2[DUAL ? 4 : 1][DUAL ? NT : 1] = {};

    // ---- staging helper: fill buffer b with K-tile at k0 ----
    auto stage = [&](int b, int k0) {
#if HAS_ASYNC
#pragma unroll
        for (int p = 0; p < BPASS; p++)
            cp16(gB + (size_t)p * 32 * K + k0, &Bs[b][(p * 32 + wave * 8) * 64]);
        if constexpr (DUAL) {
#pragma unroll
            for (int p = 0; p < BPASS; p++)
                cp16(gB2 + (size_t)p * 32 * K + k0, &B2s[b][(p * 32 + wave * 8) * 64]);
        }
#else
#pragma unroll
        for (int p = 0; p < BPASS; p++)
            *(uint4*)&Bs[b][(p * 32 + srow) * 64 + (tid & 7) * 8] =
                *(const uint4*)(gB + (size_t)p * 32 * K + k0);
        if constexpr (DUAL) {
#pragma unroll
            for (int p = 0; p < BPASS; p++)
                *(uint4*)&B2s[b][(p * 32 + srow) * 64 + (tid & 7) * 8] =
                    *(const uint4*)(gB2 + (size_t)p * 32 * K + k0);
        }
#endif
        if ((AMODE == 1) && (m0 == 0)) {
            // manual staging with zero-guard (rows m-3+dk < 0)
            int kg = k0 + scol;
            int dk = kg >> 10, ii = kg & 1023;
#pragma unroll
            for (int p = 0; p < 4; p++) {
                int msrc = p * 32 + srow + dk - 3;
                uint4 v = {0, 0, 0, 0};
                if (msrc >= 0)
                    v = *(const uint4*)(A + (size_t)msrc * 1024 + ii);
                *(uint4*)&As[b][(p * 32 + srow) * 64 + (tid & 7) * 8] = v;
            }
        } else {
#if HAS_ASYNC
#pragma unroll
            for (int p = 0; p < 4; p++)
                cp16(gA + (size_t)p * 32 * strideA + k0, &As[b][(p * 32 + wave * 8) * 64]);
#else
#pragma unroll
            for (int p = 0; p < 4; p++)
                *(uint4*)&As[b][(p * 32 + srow) * 64 + (tid & 7) * 8] =
                    *(const uint4*)(gA + (size_t)p * 32 * strideA + k0);
#endif
        }
    };

    // ---- compute helper: MFMA over buffer b ----
    auto compute = [&](int b) {
#pragma unroll
        for (int h = 0; h < 2; h++) {
            bf16x8 af[4], bfv[NT], bf2v[NT];
            int so = (((h * 4 + quad) ^ (l16 & 7)) << 3); // swizzled elem offset
#pragma unroll
            for (int i = 0; i < 4; i++)
                af[i] = *(const bf16x8*)&As[b][(wm + i * 16 + l16) * 64 + so];
#pragma unroll
            for (int j = 0; j < NT; j++) {
                bfv[j] = *(const bf16x8*)&Bs[b][(wn + j * 16 + l16) * 64 + so];
                if constexpr (DUAL)
                    bf2v[j] = *(const bf16x8*)&B2s[b][(wn + j * 16 + l16) * 64 + so];
            }
#pragma unroll
            for (int i = 0; i < 4; i++)
#pragma unroll
                for (int j = 0; j < NT; j++) {
                    acc[i][j] = __builtin_amdgcn_mfma_f32_16x16x32_bf16(af[i], bfv[j],
                                                                       acc[i][j], 0, 0, 0);
                    if constexpr (DUAL)
                        acc2[i][j] = __builtin_amdgcn_mfma_f32_16x16x32_bf16(af[i], bf2v[j],
                                                                            acc2[i][j], 0, 0, 0);
                }
        }
    };

    if constexpr (NBUF == 1) {
        for (int k0 = 0; k0 < K; k0 += 64) {
            stage(0, k0);
            __syncthreads();
            compute(0);
            __syncthreads();
        }
    } else {
        stage(0, 0);
        __syncthreads();   // buf0 ready
        int cur = 0;
        for (int k0 = 0; k0 < K; k0 += 64) {
            if (k0 + 64 < K) stage(cur ^ 1, k0 + 64);   // issue next tile EARLY
            compute(cur);
            __syncthreads();   // drains stage loads; retires buf reads
            cur ^= 1;
        }
    }

    // ---- epilogue: C/D layout col=lane&15, row=quad*4+reg ----
#pragma unroll
    for (int i = 0; i < 4; i++) {
        int mb = m0 + wm + i * 16 + quad * 4;
#pragma unroll
        for (int j = 0; j < NT; j++) {
            int n = n0 + wn + j * 16 + l16;
#pragma unroll
            for (int rg = 0; rg < 4; rg++) {
                int m = mb + rg;
                float v = acc[i][j][rg];
                if constexpr (EMODE == 0) {
                    Cb[(size_t)m * N + n] = f2us(v);
                } else if constexpr (EMODE == 1) {
                    v += bias[n];
                    if (n < 1024) Cb[((size_t)m << 10) + n] = f2us(v);
                    else          Cb2[((size_t)m << 10) + (n - 1024)] = f2us(v);
                } else if constexpr (EMODE == 2) {
                    v += bias[n];
                    if (resid) v += resid[(size_t)m * N + n];
                    Cf[(size_t)m * N + n] = v;
                } else if constexpr (EMODE == 3) {
                    float ig = fast_sigmoid(v + bias[n]);
                    float rgv = fast_sigmoid(acc2[i][j][rg] + bias2[n]);
                    float av = fast_exp(nl[n] * rgv);
                    size_t id = ((size_t)m << 10) + n;
                    Cb[id] = f2us(av);
                    Cb2[id] = f2us(sqrtf(fmaxf(1.0f - av * av, 0.0f)) * ig * us2f(cv[id]));
                } else { // EMODE 4
                    float v1 = gelu_fast(v + bias[n]);
                    float v2 = acc2[i][j][rg] + bias2[n];
                    Cb[(size_t)m * 3072 + n] = f2us(v1 * v2);
                }
            }
        }
    }
}

// ---------------------------------------------------------------------------
// Chunked linear scan over bf16 a/gx: h_t = a_t*h_{t-1} + gx_t.
// 256 chunks x 32 steps (G1: 512 blocks = 2/CU). 2 channels/thread via 4B
// uint loads (G13). Pass 3 fuses z = gelu(aba)*h (packed 4B stores).
// ---------------------------------------------------------------------------
#define NCHUNK 256
#define CHLEN 32

__global__ __launch_bounds__(256) void scan_pass1(const ushort_t* __restrict__ a16,
                                                  const ushort_t* __restrict__ g16,
                                                  float* __restrict__ Ac,
                                                  float* __restrict__ Bc) {
    int g = blockIdx.x * 256 + threadIdx.x;  // 131072 threads
    int cp = g & 511, ck = g >> 9;           // channel-pair, chunk
    int ch = cp * 2;
    size_t base = (((size_t)ck * CHLEN) << 10) + ch;
    const uint* ap = (const uint*)(a16 + base);
    const uint* gp = (const uint*)(g16 + base);
    float P0 = 1.0f, P1 = 1.0f, B0 = 0.0f, B1 = 0.0f;
#pragma unroll 8
    for (int t = 0; t < CHLEN; t++) {
        uint ua = ap[t * 512];
        uint ug = gp[t * 512];
        float a0 = us2f((ushort_t)ua), a1 = us2f((ushort_t)(ua >> 16));
        float g0 = us2f((ushort_t)ug), g1 = us2f((ushort_t)(ug >> 16));
        P0 *= a0; B0 = fmaf(a0, B0, g0);
        P1 *= a1; B1 = fmaf(a1, B1, g1);
    }
    float2 pv = {P0, P1}, bv = {B0, B1};
    *(float2*)&Ac[ck * 1024 + ch] = pv;
    *(float2*)&Bc[ck * 1024 + ch] = bv;
}

__global__ __launch_bounds__(256) void scan_pass2(const float* __restrict__ Ac,
                                                  const float* __restrict__ Bc,
                                                  float* __restrict__ Hc) {
    int ch = blockIdx.x * 256 + threadIdx.x; // 1024
    float H = 0.0f;
#pragma unroll 8
    for (int j = 0; j < NCHUNK; j++) {
        Hc[j * 1024 + ch] = H;
        H = fmaf(Ac[j * 1024 + ch], H, Bc[j * 1024 + ch]);
    }
}

__global__ __launch_bounds__(256) void scan_pass3(const ushort_t* __restrict__ a16,
                                                  const ushort_t* __restrict__ g16,
                                                  const float* __restrict__ Hc,
                                                  const ushort_t* __restrict__ aba,
                                                  ushort_t* __restrict__ z) {
    int g = blockIdx.x * 256 + threadIdx.x;
    int cp = g & 511, ck = g >> 9;
    int ch = cp * 2;
    size_t base = (((size_t)ck * CHLEN) << 10) + ch;
    float s0 = Hc[ck * 1024 + ch], s1 = Hc[ck * 1024 + ch + 1];
    const uint* ap = (const uint*)(a16 + base);
    const uint* gp = (const uint*)(g16 + base);
    const uint* bp = (const uint*)(aba + base);
    uint* zp = (uint*)(z + base);
#pragma unroll 8
    for (int t = 0; t < CHLEN; t++) {
        uint ua = ap[t * 512], ug = gp[t * 512], ub = bp[t * 512];
        s0 = fmaf(us2f((ushort_t)ua), s0, us2f((ushort_t)ug));
        s1 = fmaf(us2f((ushort_t)(ua >> 16)), s1, us2f((ushort_t)(ug >> 16)));
        float z0 = gelu_fast(us2f((ushort_t)ub)) * s0;
        float z1 = gelu_fast(us2f((ushort_t)(ub >> 16))) * s1;
        zp[t * 512] = (uint)f2us(z0) | ((uint)f2us(z1) << 16);
    }
}

// ---------------------------------------------------------------------------
extern "C" void kernel_launch(void* const* d_in, const int* in_sizes, int n_in,
                              void* d_out, int out_size, void* d_ws, size_t ws_size,
                              hipStream_t stream) {
    const float* x      = (const float*)d_in[0];
    const float* w_n1   = (const float*)d_in[1];
    const float* w_n2   = (const float*)d_in[2];
    const float* w_lin1 = (const float*)d_in[3];
    const float* b_lin1 = (const float*)d_in[4];
    const float* w_conv = (const float*)d_in[5];
    const float* w_rg   = (const float*)d_in[6];
    const float* b_rg   = (const float*)d_in[7];
    const float* Lambda = (const float*)d_in[8];
    const float* w_out  = (const float*)d_in[9];
    const float* b_out  = (const float*)d_in[10];
    const float* w_m1   = (const float*)d_in[11];
    const float* b_m1   = (const float*)d_in[12];
    const float* w_m2   = (const float*)d_in[13];
    const float* b_m2   = (const float*)d_in[14];

    char* ws = (char*)d_ws;
    const size_t MB = 1024ull * 1024ull;
    // Peak footprint 184 MB (<208 proven safe).
    ushort_t* wb   = (ushort_t*)(ws + 0);
    float*    x1   = (float*)(ws + 32 * MB);
    float*    nl   = (float*)(ws + 56 * MB);
    ushort_t* h16  = (ushort_t*)(ws + 57 * MB);
    ushort_t* aba  = (ushort_t*)(ws + 69 * MB);
    ushort_t* abb  = (ushort_t*)(ws + 85 * MB);
    ushort_t* z16  = (ushort_t*)(ws + 85 * MB);
    ushort_t* cv16 = (ushort_t*)(ws + 101 * MB);
    ushort_t* a16  = (ushort_t*)(ws + 117 * MB);
    ushort_t* gx16 = (ushort_t*)(ws + 133 * MB);
    ushort_t* gm   = (ushort_t*)(ws + 117 * MB);
    float*    Ac   = (float*)(ws + 181 * MB);
    float*    Bc   = (float*)(ws + 182 * MB);
    float*    Hc   = (float*)(ws + 183 * MB);
    float*    out  = (float*)d_out;

    ushort_t* wb_lin1 = wb + 0;          // 2048*768
    ushort_t* wb_conv = wb + 1572864;    // 1024*4096 (reordered)
    ushort_t* wb_rg   = wb + 5767168;    // 2048*1024
    ushort_t* wb_out  = wb + 7864320;    // 768*1024
    ushort_t* wb_m1   = wb + 8650752;    // 6144*768
    ushort_t* wb_m2   = wb + 13369344;   // 768*3072

    const int M = S_LEN;

    // 0. all weight conversions + nl in one launch
    cvt_all<<<61444, 256, 0, stream>>>(w_lin1, w_conv, w_rg, w_out, w_m1, w_m2,
                                       Lambda, wb, nl);
    // 1. h = rms(x, w_n1)  (4 rows/block, wave-per-row)
    rms_kernel<<<M / 4, 256, 0, stream>>>(x, w_n1, h16, D_MODEL);
    // 2. ab = h @ w_lin1^T + b_lin1, split -> aba/abb  (N=2048, K=768)
    mfma_nt<128, 0, 1><<<dim3(M / 128, 2048 / 128), 256, 0, stream>>>(
        h16, wb_lin1, nullptr, b_lin1, nullptr, nullptr, nullptr, nullptr,
        nullptr, aba, abb, M, 2048, 768);
    // 3. conv = im2col(abb) @ wb_conv^T -> cv16  (N=1024, K=4096, fused gather)
    mfma_nt<128, 1, 0><<<dim3(M / 128, 1024 / 128), 256, 0, stream>>>(
        abb, wb_conv, nullptr, nullptr, nullptr, nullptr, nullptr, nullptr,
        nullptr, cv16, nullptr, M, 1024, 4096);
    // 4. dual-B gates GEMM + gate math -> a16, gx16 bf16  (N'=1024, K=1024, BN=64)
    mfma_nt<64, 0, 3><<<dim3(M / 128, 1024 / 64), 256, 0, stream>>>(
        cv16, wb_rg, wb_rg + 1024 * 1024, b_rg, b_rg + 1024, nullptr, nl, cv16,
        nullptr, a16, gx16, M, 1024, 1024);
    // 5. chunked scan; pass3 fuses z = gelu(aba)*h -> z16
    scan_pass1<<<512, 256, 0, stream>>>(a16, gx16, Ac, Bc);
    scan_pass2<<<4, 256, 0, stream>>>(Ac, Bc, Hc);
    scan_pass3<<<512, 256, 0, stream>>>(a16, gx16, Hc, aba, z16);
    // 6. x1 = z @ w_out^T + b_out + x  (N=768, K=1024, fp32)
    mfma_nt<64, 0, 2><<<dim3(M / 128, 768 / 64), 256, 0, stream>>>(
        z16, wb_out, nullptr, b_out, nullptr, x, nullptr, nullptr,
        x1, nullptr, nullptr, M, 768, 1024);
    // 7. h2 = rms(x1, w_n2)
    rms_kernel<<<M / 4, 256, 0, stream>>>(x1, w_n2, h16, D_MODEL);
    // 8. dual-B MLP up-proj + GeGLU -> gm bf16  (N'=3072, K=768, BN=64)
    mfma_nt<64, 0, 4><<<dim3(M / 128, 3072 / 64), 256, 0, stream>>>(
        h16, wb_m1, wb_m1 + 3072 * 768, b_m1, b_m1 + 3072, nullptr, nullptr, nullptr,
        nullptr, gm, nullptr, M, 3072, 768);
    // 9. out = gm @ w_m2^T + b_m2 + x1  (N=768, K=3072, fp32)
    mfma_nt<64, 0, 2><<<dim3(M / 128, 768 / 64), 256, 0, stream>>>(
        gm, wb_m2, nullptr, b_m2, nullptr, x1, nullptr, nullptr,
        out, nullptr, nullptr, M, 768, 3072);
}

// Round 10
// 525.093 us; speedup vs baseline: 1.1611x; 1.0369x over previous
//
#include <hip/hip_runtime.h>
#include <hip/hip_bf16.h>
#include <math.h>

#define S_LEN 8192
#define D_MODEL 768
#define D_RNN 1024
#define MLP_INNER 3072

typedef __attribute__((ext_vector_type(8))) short bf16x8;
typedef __attribute__((ext_vector_type(4))) float f32x4;
typedef unsigned short ushort_t;

#ifndef __has_builtin
#define __has_builtin(x) 0
#endif
#if __has_builtin(__builtin_amdgcn_global_load_lds)
#define HAS_ASYNC 1
#else
#define HAS_ASYNC 0
#endif

#define LOG2E 1.4426950408889634f

// fast sigmoid: 1/(1+2^(-x*log2e)); v_exp_f32 + v_rcp_f32, ~1ulp
__device__ __forceinline__ float fast_sigmoid(float x) {
    float e = __builtin_amdgcn_exp2f(-x * LOG2E);
    return __builtin_amdgcn_rcpf(1.0f + e);
}
// fast exp
__device__ __forceinline__ float fast_exp(float x) {
    return __builtin_amdgcn_exp2f(x * LOG2E);
}
// gelu(tanh approx) = v * sigmoid(2*0.7978845608*(v + 0.044715 v^3))
__device__ __forceinline__ float gelu_fast(float v) {
    float u = v * (1.5957691216057308f + 0.07135481283247183f * v * v);
    return v * fast_sigmoid(u);
}
__device__ __forceinline__ float us2f(ushort_t u) { return __uint_as_float(((unsigned)u) << 16); }
__device__ __forceinline__ ushort_t f2us(float f) {
    __hip_bfloat16 b = __float2bfloat16(f);
    return *(ushort_t*)&b;
}

// async 16B global -> LDS (wave-uniform LDS base; HW adds lane*16B)
__device__ __forceinline__ void cp16(const ushort_t* g, ushort_t* l) {
#if HAS_ASYNC
    __builtin_amdgcn_global_load_lds((__attribute__((address_space(1))) void*)g,
                                     (__attribute__((address_space(3))) void*)l,
                                     16, 0, 0);
#endif
}

// ---------------------------------------------------------------------------
// One-shot weight conversion fp32 -> bf16 (all weights) + nl.
// Vectorized x4 (G13): float4 loads / ushort4 stores; every region boundary
// is a multiple of 4; conv-reorder rows (i2 span) never cross within a quad.
// ---------------------------------------------------------------------------
__global__ __launch_bounds__(256) void cvt_all(const float* __restrict__ w_lin1,
                                               const float* __restrict__ w_conv,
                                               const float* __restrict__ w_rg,
                                               const float* __restrict__ w_out,
                                               const float* __restrict__ w_m1,
                                               const float* __restrict__ w_m2,
                                               const float* __restrict__ Lambda,
                                               ushort_t* __restrict__ wb,
                                               float* __restrict__ nl) {
    int j = (blockIdx.x * 256 + threadIdx.x) * 4;
    if (j < 1572864) {
        float4 v = *(const float4*)&w_lin1[j];
        ushort4 u = {f2us(v.x), f2us(v.y), f2us(v.z), f2us(v.w)};
        *(ushort4*)&wb[j] = u;
    } else if (j < 5767168) {
        int d = j - 1572864;
        int i2 = d & 1023, dk = (d >> 10) & 3, o = d >> 12;
        const float* src = w_conv + (size_t)o * 4096 + dk;
        ushort4 u = {f2us(src[(i2 + 0) * 4]), f2us(src[(i2 + 1) * 4]),
                     f2us(src[(i2 + 2) * 4]), f2us(src[(i2 + 3) * 4])};
        *(ushort4*)&wb[j] = u;
    } else if (j < 7864320) {
        float4 v = *(const float4*)&w_rg[j - 5767168];
        ushort4 u = {f2us(v.x), f2us(v.y), f2us(v.z), f2us(v.w)};
        *(ushort4*)&wb[j] = u;
    } else if (j < 8650752) {
        float4 v = *(const float4*)&w_out[j - 7864320];
        ushort4 u = {f2us(v.x), f2us(v.y), f2us(v.z), f2us(v.w)};
        *(ushort4*)&wb[j] = u;
    } else if (j < 13369344) {
        float4 v = *(const float4*)&w_m1[j - 8650752];
        ushort4 u = {f2us(v.x), f2us(v.y), f2us(v.z), f2us(v.w)};
        *(ushort4*)&wb[j] = u;
    } else if (j < 15728640) {
        float4 v = *(const float4*)&w_m2[j - 13369344];
        ushort4 u = {f2us(v.x), f2us(v.y), f2us(v.z), f2us(v.w)};
        *(ushort4*)&wb[j] = u;
    } else {
        int c = j - 15728640;
        if (c < D_RNN) {
#pragma unroll
            for (int q = 0; q < 4; q++)
                nl[c + q] = -8.0f * log1pf(expf(Lambda[c + q]));
        }
    }
}

// ---------------------------------------------------------------------------
// RMSNorm fp32 in -> bf16 out. One wave per row (768 = 64 lanes x 3 float4),
// 4 rows per block. Row lives in registers: float4 loads, shfl butterfly
// reduce, no LDS / no syncthreads, packed 8B bf16 stores. (G13 + G1)
// ---------------------------------------------------------------------------
__global__ __launch_bounds__(256) void rms_kernel(const float* __restrict__ x,
                                                  const float* __restrict__ w,
                                                  ushort_t* __restrict__ o, int D) {
    int wid = threadIdx.x >> 6, lane = threadIdx.x & 63;
    int row = blockIdx.x * 4 + wid;
    const float4* xr = (const float4*)(x + (size_t)row * 768);
    const float4* wr = (const float4*)w;
    float4 v0 = xr[lane], v1 = xr[lane + 64], v2 = xr[lane + 128];
    float ss = v0.x * v0.x + v0.y * v0.y + v0.z * v0.z + v0.w * v0.w +
               v1.x * v1.x + v1.y * v1.y + v1.z * v1.z + v1.w * v1.w +
               v2.x * v2.x + v2.y * v2.y + v2.z * v2.z + v2.w * v2.w;
#pragma unroll
    for (int off = 32; off > 0; off >>= 1) ss += __shfl_xor(ss, off);
    float s = rsqrtf(ss * (1.0f / 768.0f) + 1e-5f);
    float4 w0 = wr[lane], w1 = wr[lane + 64], w2 = wr[lane + 128];
    ushort_t* orow = o + (size_t)row * 768;
    ushort4 u0 = {f2us(v0.x * s * w0.x), f2us(v0.y * s * w0.y),
                  f2us(v0.z * s * w0.z), f2us(v0.w * s * w0.w)};
    ushort4 u1 = {f2us(v1.x * s * w1.x), f2us(v1.y * s * w1.y),
                  f2us(v1.z * s * w1.z), f2us(v1.w * s * w1.w)};
    ushort4 u2 = {f2us(v2.x * s * w2.x), f2us(v2.y * s * w2.y),
                  f2us(v2.z * s * w2.z), f2us(v2.w * s * w2.w)};
    *(ushort4*)&orow[4 * lane] = u0;
    *(ushort4*)&orow[256 + 4 * lane] = u1;
    *(ushort4*)&orow[512 + 4 * lane] = u2;
}

// ---------------------------------------------------------------------------
// MFMA bf16 NT GEMM, 128xBN_ tile, 4 waves (2x2), BK=64.
// NBUF rule (all HW-verified on this problem):
//   EMODE 4 (GeGLU dual):  NBUF=1, BN=64 — single-buf beat dbuf 96.2 vs
//     102.4 us (r9 vs r7); BN=128-dual is a register cliff (r8: 280 regs
//     -> 1 wave/SIMD -> -67%). Dual caps at NT=2.
//   everything else:       NBUF=2 (2-phase dbuf: STAGE(next) before
//     compute(cur), one barrier/K-step) — r7 win on long-K non-dual.
// Staging swizzle: thread owns (srow=tid>>3, slot=tid&7); LDS row r slot s
// holds global 16B-chunk s^(r&7). Fragment read: chunk (h*4+quad)^(l16&7).
// AMODE 0: A[M,K] bf16 row-major.  AMODE 1: conv im2col, element (m,k) =
//   abb[(m-3)*1024 + k]; m0==0 staged manually with zero-guard.
// EMODE 0: bf16 -> Cb[M,N]
// EMODE 1: +bias, split halves -> Cb (n<1024), Cb2 (n>=1024), stride 1024
// EMODE 2: +bias +resid -> fp32 Cf[M,N]
// EMODE 3: dual-B gates -> bf16 a=Cb, gx=Cb2 (stride 1024)
// EMODE 4: dual-B geglu: Cb[m*3072+n] = gelu(acc1+b1)*(acc2+b2)
// ---------------------------------------------------------------------------
template <int BN_, int AMODE, int EMODE>
__global__ __launch_bounds__(256) void mfma_nt(const ushort_t* __restrict__ A,
                                               const ushort_t* __restrict__ B,
                                               const ushort_t* __restrict__ B2,
                                               const float* __restrict__ bias,
                                               const float* __restrict__ bias2,
                                               const float* __restrict__ resid,
                                               const float* __restrict__ nl,
                                               const ushort_t* __restrict__ cv,
                                               float* __restrict__ Cf,
                                               ushort_t* __restrict__ Cb,
                                               ushort_t* __restrict__ Cb2,
                                               int M, int N, int K) {
    constexpr bool DUAL = (EMODE == 3 || EMODE == 4);
    constexpr int NBUF = (EMODE == 4) ? 1 : 2;
    constexpr int NT = BN_ / 32;           // n-tiles per wave
    constexpr int BPASS = BN_ / 32;        // 32-row staging passes for B
    __shared__ ushort_t As[NBUF][128 * 64];
    __shared__ ushort_t Bs[NBUF][BN_ * 64];
    __shared__ ushort_t B2s[DUAL ? NBUF : 1][DUAL ? BN_ * 64 : 8];

    int tid = threadIdx.x;
    int wave = tid >> 6, lane = tid & 63;
    int quad = lane >> 4, l16 = lane & 15;
    int wm = (wave >> 1) * 64, wn = (wave & 1) * (BN_ / 2);
    int m0 = blockIdx.x * 128, n0 = blockIdx.y * BN_;
    int srow = tid >> 3;                      // staging row 0..31 (per pass)
    int scol = (((tid & 7) ^ (srow & 7)) * 8); // XOR-swizzled staging k-offset

    const int strideA = (AMODE == 0) ? K : 1024;
    const ushort_t* gA = A + (size_t)(m0 + srow - (AMODE == 1 ? 3 : 0)) * strideA + scol;
    const ushort_t* gB = B + (size_t)(n0 + srow) * K + scol;
    const ushort_t* gB2 = DUAL ? (B2 + (size_t)(n0 + srow) * K + scol) : nullptr;

    f32x4 acc[4][NT] = {};
    f32x4 acc2[DUAL ? 4 : 1][DUAL ? NT : 1] = {};

    // ---- staging helper: fill buffer b with K-tile at k0 ----
    auto stage = [&](int b, int k0) {
#if HAS_ASYNC
#pragma unroll
        for (int p = 0; p < BPASS; p++)
            cp16(gB + (size_t)p * 32 * K + k0, &Bs[b][(p * 32 + wave * 8) * 64]);
        if constexpr (DUAL) {
#pragma unroll
            for (int p = 0; p < BPASS; p++)
                cp16(gB2 + (size_t)p * 32 * K + k0, &B2s[b][(p * 32 + wave * 8) * 64]);
        }
#else
#pragma unroll
        for (int p = 0; p < BPASS; p++)
            *(uint4*)&Bs[b][(p * 32 + srow) * 64 + (tid & 7) * 8] =
                *(const uint4*)(gB + (size_t)p * 32 * K + k0);
        if constexpr (DUAL) {
#pragma unroll
            for (int p = 0; p < BPASS; p++)
                *(uint4*)&B2s[b][(p * 32 + srow) * 64 + (tid & 7) * 8] =
                    *(const uint4*)(gB2 + (size_t)p * 32 * K + k0);
        }
#endif
        if ((AMODE == 1) && (m0 == 0)) {
            // manual staging with zero-guard (rows m-3+dk < 0)
            int kg = k0 + scol;
            int dk = kg >> 10, ii = kg & 1023;
#pragma unroll
            for (int p = 0; p < 4; p++) {
                int msrc = p * 32 + srow + dk - 3;
                uint4 v = {0, 0, 0, 0};
                if (msrc >= 0)
                    v = *(const uint4*)(A + (size_t)msrc * 1024 + ii);
                *(uint4*)&As[b][(p * 32 + srow) * 64 + (tid & 7) * 8] = v;
            }
        } else {
#if HAS_ASYNC
#pragma unroll
            for (int p = 0; p < 4; p++)
                cp16(gA + (size_t)p * 32 * strideA + k0, &As[b][(p * 32 + wave * 8) * 64]);
#else
#pragma unroll
            for (int p = 0; p < 4; p++)
                *(uint4*)&As[b][(p * 32 + srow) * 64 + (tid & 7) * 8] =
                    *(const uint4*)(gA + (size_t)p * 32 * strideA + k0);
#endif
        }
    };

    // ---- compute helper: MFMA over buffer b ----
    auto compute = [&](int b) {
#pragma unroll
        for (int h = 0; h < 2; h++) {
            bf16x8 af[4], bfv[NT], bf2v[NT];
            int so = (((h * 4 + quad) ^ (l16 & 7)) << 3); // swizzled elem offset
#pragma unroll
            for (int i = 0; i < 4; i++)
                af[i] = *(const bf16x8*)&As[b][(wm + i * 16 + l16) * 64 + so];
#pragma unroll
            for (int j = 0; j < NT; j++) {
                bfv[j] = *(const bf16x8*)&Bs[b][(wn + j * 16 + l16) * 64 + so];
                if constexpr (DUAL)
                    bf2v[j] = *(const bf16x8*)&B2s[b][(wn + j * 16 + l16) * 64 + so];
            }
#pragma unroll
            for (int i = 0; i < 4; i++)
#pragma unroll
                for (int j = 0; j < NT; j++) {
                    acc[i][j] = __builtin_amdgcn_mfma_f32_16x16x32_bf16(af[i], bfv[j],
                                                                       acc[i][j], 0, 0, 0);
                    if constexpr (DUAL)
                        acc2[i][j] = __builtin_amdgcn_mfma_f32_16x16x32_bf16(af[i], bf2v[j],
                                                                            acc2[i][j], 0, 0, 0);
                }
        }
    };

    if constexpr (NBUF == 1) {
        for (int k0 = 0; k0 < K; k0 += 64) {
            stage(0, k0);
            __syncthreads();
            compute(0);
            __syncthreads();
        }
    } else {
        stage(0, 0);
        __syncthreads();   // buf0 ready
        int cur = 0;
        for (int k0 = 0; k0 < K; k0 += 64) {
            if (k0 + 64 < K) stage(cur ^ 1, k0 + 64);   // issue next tile EARLY
            compute(cur);
            __syncthreads();   // drains stage loads; retires buf reads
            cur ^= 1;
        }
    }

    // ---- epilogue: C/D layout col=lane&15, row=quad*4+reg ----
#pragma unroll
    for (int i = 0; i < 4; i++) {
        int mb = m0 + wm + i * 16 + quad * 4;
#pragma unroll
        for (int j = 0; j < NT; j++) {
            int n = n0 + wn + j * 16 + l16;
#pragma unroll
            for (int rg = 0; rg < 4; rg++) {
                int m = mb + rg;
                float v = acc[i][j][rg];
                if constexpr (EMODE == 0) {
                    Cb[(size_t)m * N + n] = f2us(v);
                } else if constexpr (EMODE == 1) {
                    v += bias[n];
                    if (n < 1024) Cb[((size_t)m << 10) + n] = f2us(v);
                    else          Cb2[((size_t)m << 10) + (n - 1024)] = f2us(v);
                } else if constexpr (EMODE == 2) {
                    v += bias[n];
                    if (resid) v += resid[(size_t)m * N + n];
                    Cf[(size_t)m * N + n] = v;
                } else if constexpr (EMODE == 3) {
                    float ig = fast_sigmoid(v + bias[n]);
                    float rgv = fast_sigmoid(acc2[i][j][rg] + bias2[n]);
                    float av = fast_exp(nl[n] * rgv);
                    size_t id = ((size_t)m << 10) + n;
                    Cb[id] = f2us(av);
                    Cb2[id] = f2us(sqrtf(fmaxf(1.0f - av * av, 0.0f)) * ig * us2f(cv[id]));
                } else { // EMODE 4
                    float v1 = gelu_fast(v + bias[n]);
                    float v2 = acc2[i][j][rg] + bias2[n];
                    Cb[(size_t)m * 3072 + n] = f2us(v1 * v2);
                }
            }
        }
    }
}

// ---------------------------------------------------------------------------
// Chunked linear scan over bf16 a/gx: h_t = a_t*h_{t-1} + gx_t.
// 256 chunks x 32 steps (G1: 512 blocks = 2/CU). 2 channels/thread via 4B
// uint loads (G13). Pass 3 fuses z = gelu(aba)*h (packed 4B stores).
// ---------------------------------------------------------------------------
#define NCHUNK 256
#define CHLEN 32

__global__ __launch_bounds__(256) void scan_pass1(const ushort_t* __restrict__ a16,
                                                  const ushort_t* __restrict__ g16,
                                                  float* __restrict__ Ac,
                                                  float* __restrict__ Bc) {
    int g = blockIdx.x * 256 + threadIdx.x;  // 131072 threads
    int cp = g & 511, ck = g >> 9;           // channel-pair, chunk
    int ch = cp * 2;
    size_t base = (((size_t)ck * CHLEN) << 10) + ch;
    const uint* ap = (const uint*)(a16 + base);
    const uint* gp = (const uint*)(g16 + base);
    float P0 = 1.0f, P1 = 1.0f, B0 = 0.0f, B1 = 0.0f;
#pragma unroll 8
    for (int t = 0; t < CHLEN; t++) {
        uint ua = ap[t * 512];
        uint ug = gp[t * 512];
        float a0 = us2f((ushort_t)ua), a1 = us2f((ushort_t)(ua >> 16));
        float g0 = us2f((ushort_t)ug), g1 = us2f((ushort_t)(ug >> 16));
        P0 *= a0; B0 = fmaf(a0, B0, g0);
        P1 *= a1; B1 = fmaf(a1, B1, g1);
    }
    float2 pv = {P0, P1}, bv = {B0, B1};
    *(float2*)&Ac[ck * 1024 + ch] = pv;
    *(float2*)&Bc[ck * 1024 + ch] = bv;
}

__global__ __launch_bounds__(256) void scan_pass2(const float* __restrict__ Ac,
                                                  const float* __restrict__ Bc,
                                                  float* __restrict__ Hc) {
    int ch = blockIdx.x * 256 + threadIdx.x; // 1024
    float H = 0.0f;
#pragma unroll 8
    for (int j = 0; j < NCHUNK; j++) {
        Hc[j * 1024 + ch] = H;
        H = fmaf(Ac[j * 1024 + ch], H, Bc[j * 1024 + ch]);
    }
}

__global__ __launch_bounds__(256) void scan_pass3(const ushort_t* __restrict__ a16,
                                                  const ushort_t* __restrict__ g16,
                                                  const float* __restrict__ Hc,
                                                  const ushort_t* __restrict__ aba,
                                                  ushort_t* __restrict__ z) {
    int g = blockIdx.x * 256 + threadIdx.x;
    int cp = g & 511, ck = g >> 9;
    int ch = cp * 2;
    size_t base = (((size_t)ck * CHLEN) << 10) + ch;
    float s0 = Hc[ck * 1024 + ch], s1 = Hc[ck * 1024 + ch + 1];
    const uint* ap = (const uint*)(a16 + base);
    const uint* gp = (const uint*)(g16 + base);
    const uint* bp = (const uint*)(aba + base);
    uint* zp = (uint*)(z + base);
#pragma unroll 8
    for (int t = 0; t < CHLEN; t++) {
        uint ua = ap[t * 512], ug = gp[t * 512], ub = bp[t * 512];
        s0 = fmaf(us2f((ushort_t)ua), s0, us2f((ushort_t)ug));
        s1 = fmaf(us2f((ushort_t)(ua >> 16)), s1, us2f((ushort_t)(ug >> 16)));
        float z0 = gelu_fast(us2f((ushort_t)ub)) * s0;
        float z1 = gelu_fast(us2f((ushort_t)(ub >> 16))) * s1;
        zp[t * 512] = (uint)f2us(z0) | ((uint)f2us(z1) << 16);
    }
}

// ---------------------------------------------------------------------------
extern "C" void kernel_launch(void* const* d_in, const int* in_sizes, int n_in,
                              void* d_out, int out_size, void* d_ws, size_t ws_size,
                              hipStream_t stream) {
    const float* x      = (const float*)d_in[0];
    const float* w_n1   = (const float*)d_in[1];
    const float* w_n2   = (const float*)d_in[2];
    const float* w_lin1 = (const float*)d_in[3];
    const float* b_lin1 = (const float*)d_in[4];
    const float* w_conv = (const float*)d_in[5];
    const float* w_rg   = (const float*)d_in[6];
    const float* b_rg   = (const float*)d_in[7];
    const float* Lambda = (const float*)d_in[8];
    const float* w_out  = (const float*)d_in[9];
    const float* b_out  = (const float*)d_in[10];
    const float* w_m1   = (const float*)d_in[11];
    const float* b_m1   = (const float*)d_in[12];
    const float* w_m2   = (const float*)d_in[13];
    const float* b_m2   = (const float*)d_in[14];

    char* ws = (char*)d_ws;
    const size_t MB = 1024ull * 1024ull;
    // Peak footprint 184 MB (<208 proven safe).
    ushort_t* wb   = (ushort_t*)(ws + 0);
    float*    x1   = (float*)(ws + 32 * MB);
    float*    nl   = (float*)(ws + 56 * MB);
    ushort_t* h16  = (ushort_t*)(ws + 57 * MB);
    ushort_t* aba  = (ushort_t*)(ws + 69 * MB);
    ushort_t* abb  = (ushort_t*)(ws + 85 * MB);
    ushort_t* z16  = (ushort_t*)(ws + 85 * MB);
    ushort_t* cv16 = (ushort_t*)(ws + 101 * MB);
    ushort_t* a16  = (ushort_t*)(ws + 117 * MB);
    ushort_t* gx16 = (ushort_t*)(ws + 133 * MB);
    ushort_t* gm   = (ushort_t*)(ws + 117 * MB);
    float*    Ac   = (float*)(ws + 181 * MB);
    float*    Bc   = (float*)(ws + 182 * MB);
    float*    Hc   = (float*)(ws + 183 * MB);
    float*    out  = (float*)d_out;

    ushort_t* wb_lin1 = wb + 0;          // 2048*768
    ushort_t* wb_conv = wb + 1572864;    // 1024*4096 (reordered)
    ushort_t* wb_rg   = wb + 5767168;    // 2048*1024
    ushort_t* wb_out  = wb + 7864320;    // 768*1024
    ushort_t* wb_m1   = wb + 8650752;    // 6144*768
    ushort_t* wb_m2   = wb + 13369344;   // 768*3072

    const int M = S_LEN;

    // 0. all weight conversions + nl in one launch (x4 vectorized)
    cvt_all<<<15361, 256, 0, stream>>>(w_lin1, w_conv, w_rg, w_out, w_m1, w_m2,
                                       Lambda, wb, nl);
    // 1. h = rms(x, w_n1)  (4 rows/block, wave-per-row)
    rms_kernel<<<M / 4, 256, 0, stream>>>(x, w_n1, h16, D_MODEL);
    // 2. ab = h @ w_lin1^T + b_lin1, split -> aba/abb  (N=2048, K=768)
    mfma_nt<128, 0, 1><<<dim3(M / 128, 2048 / 128), 256, 0, stream>>>(
        h16, wb_lin1, nullptr, b_lin1, nullptr, nullptr, nullptr, nullptr,
        nullptr, aba, abb, M, 2048, 768);
    // 3. conv = im2col(abb) @ wb_conv^T -> cv16  (N=1024, K=4096, fused gather)
    mfma_nt<128, 1, 0><<<dim3(M / 128, 1024 / 128), 256, 0, stream>>>(
        abb, wb_conv, nullptr, nullptr, nullptr, nullptr, nullptr, nullptr,
        nullptr, cv16, nullptr, M, 1024, 4096);
    // 4. dual-B gates GEMM + gate math -> a16, gx16 bf16  (N'=1024, K=1024,
    //    BN=64, NBUF=2: dbuf gates was the r7 config; r9 single-buf may have
    //    cost ~15us here)
    mfma_nt<64, 0, 3><<<dim3(M / 128, 1024 / 64), 256, 0, stream>>>(
        cv16, wb_rg, wb_rg + 1024 * 1024, b_rg, b_rg + 1024, nullptr, nl, cv16,
        nullptr, a16, gx16, M, 1024, 1024);
    // 5. chunked scan; pass3 fuses z = gelu(aba)*h -> z16
    scan_pass1<<<512, 256, 0, stream>>>(a16, gx16, Ac, Bc);
    scan_pass2<<<4, 256, 0, stream>>>(Ac, Bc, Hc);
    scan_pass3<<<512, 256, 0, stream>>>(a16, gx16, Hc, aba, z16);
    // 6. x1 = z @ w_out^T + b_out + x  (N=768, K=1024, fp32)
    mfma_nt<64, 0, 2><<<dim3(M / 128, 768 / 64), 256, 0, stream>>>(
        z16, wb_out, nullptr, b_out, nullptr, x, nullptr, nullptr,
        x1, nullptr, nullptr, M, 768, 1024);
    // 7. h2 = rms(x1, w_n2)
    rms_kernel<<<M / 4, 256, 0, stream>>>(x1, w_n2, h16, D_MODEL);
    // 8. dual-B MLP up-proj + GeGLU -> gm bf16  (N'=3072, K=768, BN=64,
    //    NBUF=1: single-buf verified best, 96.2us r9)
    mfma_nt<64, 0, 4><<<dim3(M / 128, 3072 / 64), 256, 0, stream>>>(
        h16, wb_m1, wb_m1 + 3072 * 768, b_m1, b_m1 + 3072, nullptr, nullptr, nullptr,
        nullptr, gm, nullptr, M, 3072, 768);
    // 9. out = gm @ w_m2^T + b_m2 + x1  (N=768, K=3072, fp32)
    mfma_nt<64, 0, 2><<<dim3(M / 128, 768 / 64), 256, 0, stream>>>(
        gm, wb_m2, nullptr, b_m2, nullptr, x1, nullptr, nullptr,
        out, nullptr, nullptr, M, 768, 3072);
}